// Round 1
// baseline (490.731 us; speedup 1.0000x reference)
//
#include <hip/hip_runtime.h>

#define EPS 1e-8f
#define LEAK 0.2f

#define B 8
#define CIN 256
#define F 128
#define L 2048
#define LU 4096
#define Z 256
#define NZ 100

#define LT 64
#define CC 64

// ---------------- styles: s1 = istyle@s1w.T + b + 1, s2, srgbS=(srgb+1)*rgb_conv_w ----
__global__ void k_styles(const float* __restrict__ istyle,
                         const float* __restrict__ s1w, const float* __restrict__ s1b,
                         const float* __restrict__ s2w, const float* __restrict__ s2b,
                         const float* __restrict__ rgbw, const float* __restrict__ rgbb,
                         const float* __restrict__ rgbcw,
                         float* __restrict__ s1, float* __restrict__ s2,
                         float* __restrict__ srgbS) {
    __shared__ float is[Z];
    int b = blockIdx.x;
    int t = threadIdx.x;
    if (t < Z) is[t] = istyle[b * Z + t];
    __syncthreads();
    // s1 for c = t
    {
        float acc = 0.f;
        const float* w = s1w + (size_t)t * Z;
        for (int z = 0; z < Z; ++z) acc += is[z] * w[z];
        s1[b * CIN + t] = acc + s1b[t] + 1.0f;
    }
    if (t < F) {
        float a2 = 0.f, a3 = 0.f;
        const float* w2 = s2w + (size_t)t * Z;
        const float* w3 = rgbw + (size_t)t * Z;
        for (int z = 0; z < Z; ++z) { a2 += is[z] * w2[z]; a3 += is[z] * w3[z]; }
        s2[b * F + t] = a2 + s2b[t] + 1.0f;
        srgbS[b * F + t] = (a3 + rgbb[t] + 1.0f) * rgbcw[t];
    }
}

// ---------------- demod factors d[b][f] = rsqrt(sum_c s^2 * sum_k W^2 + eps) ----------
__global__ void k_demod(const float* __restrict__ s1, const float* __restrict__ s2,
                        const float* __restrict__ W1, const float* __restrict__ W2,
                        float* __restrict__ d1, float* __restrict__ d2) {
    int b = blockIdx.x;
    int t = threadIdx.x;
    __shared__ float sh1[CIN];
    __shared__ float sh2[F];
    if (t < CIN) sh1[t] = s1[b * CIN + t];
    if (t < F) sh2[t] = s2[b * F + t];
    __syncthreads();
    if (t < F) {
        float acc = 0.f;
        const float* w = W1 + (size_t)t * CIN * 3;
        for (int c = 0; c < CIN; ++c) {
            float s = sh1[c];
            float w0 = w[c * 3], w1 = w[c * 3 + 1], w2 = w[c * 3 + 2];
            acc += s * s * (w0 * w0 + w1 * w1 + w2 * w2);
        }
        d1[b * F + t] = rsqrtf(acc + EPS);
    } else {
        int f = t - F;
        float acc = 0.f;
        const float* w = W2 + (size_t)f * F * 3;
        for (int c = 0; c < F; ++c) {
            float s = sh2[c];
            float w0 = w[c * 3], w1 = w[c * 3 + 1], w2 = w[c * 3 + 2];
            acc += s * s * (w0 * w0 + w1 * w1 + w2 * w2);
        }
        d2[b * F + f] = rsqrtf(acc + EPS);
    }
}

// ---------------- conv1: upsample(x)*s1 conv W1 -> out (pre-demod) --------------------
__launch_bounds__(256)
__global__ void k_conv1(const float* __restrict__ x, const float* __restrict__ s1,
                        const float* __restrict__ W1, float* __restrict__ out) {
    int b = blockIdx.y;
    int l0 = blockIdx.x * LT;
    int t = threadIdx.x;
    int f = t & (F - 1);
    int loff = (t >> 7) * 32;  // 0 or 32
    __shared__ float xs[CC][LT + 2];
    __shared__ float s1s[CIN];
    if (t < CIN) s1s[t] = s1[b * CIN + t];
    float acc[32];
#pragma unroll
    for (int i = 0; i < 32; ++i) acc[i] = 0.f;
    const float* xb = x + (size_t)b * CIN * L;
    for (int cb = 0; cb < CIN / CC; ++cb) {
        __syncthreads();
        for (int idx = t; idx < CC * (LT + 2); idx += 256) {
            int cc = idx / (LT + 2);
            int p = idx - cc * (LT + 2);
            int c = cb * CC + cc;
            int l = l0 - 1 + p;
            float v = 0.f;
            if (l >= 0 && l < LU) {
                const float* xr = xb + (size_t)c * L;
                int j = l >> 1;
                if (l & 1) {
                    int j1 = (j + 1 < L) ? j + 1 : L - 1;
                    v = 0.75f * xr[j] + 0.25f * xr[j1];
                } else {
                    v = (j == 0) ? xr[0] : (0.25f * xr[j - 1] + 0.75f * xr[j]);
                }
                v *= s1s[c];
            }
            xs[cc][p] = v;
        }
        __syncthreads();
        const float* wbase = W1 + ((size_t)f * CIN + cb * CC) * 3;
        for (int cc = 0; cc < CC; ++cc) {
            float w0 = wbase[cc * 3 + 0], w1 = wbase[cc * 3 + 1], w2 = wbase[cc * 3 + 2];
            const float* row = &xs[cc][loff];
            float a0 = row[0], a1 = row[1];
#pragma unroll
            for (int li = 0; li < 32; ++li) {
                float a2 = row[li + 2];
                acc[li] += a0 * w0 + a1 * w1 + a2 * w2;
                a0 = a1; a1 = a2;
            }
        }
    }
    float* ob = out + ((size_t)b * F + f) * LU + l0 + loff;
#pragma unroll
    for (int li = 0; li < 32; ++li) ob[li] = acc[li];
}

// ---------------- conv2: y1*s2 conv W2 -> out (pre-demod) -----------------------------
__launch_bounds__(256)
__global__ void k_conv2(const float* __restrict__ y1, const float* __restrict__ s2,
                        const float* __restrict__ W2, float* __restrict__ out) {
    int b = blockIdx.y;
    int l0 = blockIdx.x * LT;
    int t = threadIdx.x;
    int f = t & (F - 1);
    int loff = (t >> 7) * 32;
    __shared__ float xs[CC][LT + 2];
    __shared__ float s2s[F];
    if (t < F) s2s[t] = s2[b * F + t];
    float acc[32];
#pragma unroll
    for (int i = 0; i < 32; ++i) acc[i] = 0.f;
    const float* yb = y1 + (size_t)b * F * LU;
    for (int cb = 0; cb < F / CC; ++cb) {
        __syncthreads();
        for (int idx = t; idx < CC * (LT + 2); idx += 256) {
            int cc = idx / (LT + 2);
            int p = idx - cc * (LT + 2);
            int c = cb * CC + cc;
            int l = l0 - 1 + p;
            float v = 0.f;
            if (l >= 0 && l < LU) {
                v = yb[(size_t)c * LU + l] * s2s[c];
            }
            xs[cc][p] = v;
        }
        __syncthreads();
        const float* wbase = W2 + ((size_t)f * F + cb * CC) * 3;
        for (int cc = 0; cc < CC; ++cc) {
            float w0 = wbase[cc * 3 + 0], w1 = wbase[cc * 3 + 1], w2 = wbase[cc * 3 + 2];
            const float* row = &xs[cc][loff];
            float a0 = row[0], a1 = row[1];
#pragma unroll
            for (int li = 0; li < 32; ++li) {
                float a2 = row[li + 2];
                acc[li] += a0 * w0 + a1 * w1 + a2 * w2;
                a0 = a1; a1 = a2;
            }
        }
    }
    float* ob = out + ((size_t)b * F + f) * LU + l0 + loff;
#pragma unroll
    for (int li = 0; li < 32; ++li) ob[li] = acc[li];
}

// ---------------- noise + demod + lrelu: out = lrelu(pre*d + inoise@nw.T) -------------
__launch_bounds__(256)
__global__ void k_noise(const float* __restrict__ pre, const float* __restrict__ nw,
                        const float* __restrict__ inoise, const float* __restrict__ d,
                        float* __restrict__ out) {
    int t = threadIdx.x;
    int i = blockIdx.x * 256 + t;  // row index in [0, F*LU)
    __shared__ float ns[B][NZ];
    for (int idx = t; idx < B * NZ; idx += 256) ns[idx / NZ][idx % NZ] = inoise[idx];
    __syncthreads();
    int f = i >> 12;  // / LU
    const float* row = nw + (size_t)i * NZ;
    float acc[B];
#pragma unroll
    for (int b = 0; b < B; ++b) acc[b] = 0.f;
    for (int z = 0; z < NZ; z += 4) {
        float4 v = *reinterpret_cast<const float4*>(row + z);
#pragma unroll
        for (int b = 0; b < B; ++b) {
            acc[b] += v.x * ns[b][z] + v.y * ns[b][z + 1] + v.z * ns[b][z + 2] + v.w * ns[b][z + 3];
        }
    }
#pragma unroll
    for (int b = 0; b < B; ++b) {
        float val = pre[(size_t)b * F * LU + i] * d[b * F + f] + acc[b];
        out[(size_t)b * F * LU + i] = (val >= 0.f) ? val : LEAK * val;
    }
}

// ---------------- rgb reduce: rgb_pre[b][l] = sum_f x[b,f,l]*srgbS[b,f] + prev --------
__global__ void k_rgb1(const float* __restrict__ xf, const float* __restrict__ srgbS,
                       const float* __restrict__ prev, float* __restrict__ rgb_pre) {
    int b = blockIdx.y;
    int l = blockIdx.x * 256 + threadIdx.x;
    __shared__ float ss[F];
    if (threadIdx.x < F) ss[threadIdx.x] = srgbS[b * F + threadIdx.x];
    __syncthreads();
    float acc = prev[b * LU + l];
    const float* xb = xf + (size_t)b * F * LU + l;
    for (int f = 0; f < F; ++f) acc += xb[(size_t)f * LU] * ss[f];
    rgb_pre[b * LU + l] = acc;
}

// ---------------- rgb upsample 2x ------------------------------------------------------
__global__ void k_rgb2(const float* __restrict__ rgb_pre, float* __restrict__ rgb) {
    int i = blockIdx.x * 256 + threadIdx.x;  // [0, B*2*LU)
    int b = i >> 13;  // / 8192
    int lo = i & 8191;
    const float* r = rgb_pre + b * LU;
    float v;
    int j = lo >> 1;
    if (lo & 1) {
        int j1 = (j + 1 < LU) ? j + 1 : LU - 1;
        v = 0.75f * r[j] + 0.25f * r[j1];
    } else {
        v = (j == 0) ? r[0] : (0.25f * r[j - 1] + 0.75f * r[j]);
    }
    rgb[i] = v;
}

extern "C" void kernel_launch(void* const* d_in, const int* in_sizes, int n_in,
                              void* d_out, int out_size, void* d_ws, size_t ws_size,
                              hipStream_t stream) {
    const float* x      = (const float*)d_in[0];
    const float* prev   = (const float*)d_in[1];
    const float* istyle = (const float*)d_in[2];
    const float* inoise = (const float*)d_in[3];
    const float* s1w    = (const float*)d_in[4];
    const float* s1b    = (const float*)d_in[5];
    const float* W1     = (const float*)d_in[6];
    const float* nw1    = (const float*)d_in[7];
    const float* s2w    = (const float*)d_in[8];
    const float* s2b    = (const float*)d_in[9];
    const float* W2     = (const float*)d_in[10];
    const float* nw2    = (const float*)d_in[11];
    const float* rgbw   = (const float*)d_in[12];
    const float* rgbb   = (const float*)d_in[13];
    const float* rgbcw  = (const float*)d_in[14];

    float* ws = (float*)d_ws;
    float* s1      = ws;               // 2048
    float* s2      = s1 + 2048;        // 1024
    float* srgbS   = s2 + 1024;        // 1024
    float* d1      = srgbS + 1024;     // 1024
    float* d2      = d1 + 1024;        // 1024
    float* rgb_pre = d2 + 1024;        // 32768
    float* y1      = rgb_pre + 32768;  // 4194304

    float* xout   = (float*)d_out;               // B*F*LU
    float* rgbout = xout + (size_t)B * F * LU;   // B*2*LU

    k_styles<<<8, 256, 0, stream>>>(istyle, s1w, s1b, s2w, s2b, rgbw, rgbb, rgbcw,
                                    s1, s2, srgbS);
    k_demod<<<8, 256, 0, stream>>>(s1, s2, W1, W2, d1, d2);
    k_conv1<<<dim3(LU / LT, B), 256, 0, stream>>>(x, s1, W1, y1);
    k_noise<<<F * LU / 256, 256, 0, stream>>>(y1, nw1, inoise, d1, y1);
    k_conv2<<<dim3(LU / LT, B), 256, 0, stream>>>(y1, s2, W2, xout);
    k_noise<<<F * LU / 256, 256, 0, stream>>>(xout, nw2, inoise, d2, xout);
    k_rgb1<<<dim3(LU / 256, B), 256, 0, stream>>>(xout, srgbS, prev, rgb_pre);
    k_rgb2<<<B * 2 * LU / 256, 256, 0, stream>>>(rgb_pre, rgbout);
}

// Round 5
// 312.063 us; speedup vs baseline: 1.5725x; 1.5725x over previous
//
#include <hip/hip_runtime.h>

#define EPS 1e-8f
#define LEAK 0.2f

#define B 8
#define CIN 256
#define F 128
#define L 2048
#define LU 4096
#define Z 256
#define NZ 100
#define S (F * LU)

typedef __attribute__((ext_vector_type(8))) short bf16x8;
typedef __attribute__((ext_vector_type(4))) float f32x4;

__device__ inline unsigned short f2bf(float x) {
    unsigned u = __builtin_bit_cast(unsigned, x);
    u += 0x7fffu + ((u >> 16) & 1u);
    return (unsigned short)(u >> 16);
}
__device__ inline float bf2f(unsigned short h) {
    unsigned u = ((unsigned)h) << 16;
    return __builtin_bit_cast(float, u);
}

// ---------------- styles ----------------
__global__ void k_styles(const float* __restrict__ istyle,
                         const float* __restrict__ s1w, const float* __restrict__ s1b,
                         const float* __restrict__ s2w, const float* __restrict__ s2b,
                         const float* __restrict__ rgbw, const float* __restrict__ rgbb,
                         const float* __restrict__ rgbcw,
                         float* __restrict__ s1, float* __restrict__ s2,
                         float* __restrict__ srgbS) {
    __shared__ float is[Z];
    int b = blockIdx.x;
    int t = threadIdx.x;
    if (t < Z) is[t] = istyle[b * Z + t];
    __syncthreads();
    {
        float acc = 0.f;
        const float* w = s1w + (size_t)t * Z;
        for (int z = 0; z < Z; ++z) acc += is[z] * w[z];
        s1[b * CIN + t] = acc + s1b[t] + 1.0f;
    }
    if (t < F) {
        float a2 = 0.f, a3 = 0.f;
        const float* w2 = s2w + (size_t)t * Z;
        const float* w3 = rgbw + (size_t)t * Z;
        for (int z = 0; z < Z; ++z) { a2 += is[z] * w2[z]; a3 += is[z] * w3[z]; }
        s2[b * F + t] = a2 + s2b[t] + 1.0f;
        srgbS[b * F + t] = (a3 + rgbb[t] + 1.0f) * rgbcw[t];
    }
}

// ---------------- demod factors ----------------
__global__ void k_demod(const float* __restrict__ s1, const float* __restrict__ s2,
                        const float* __restrict__ W1, const float* __restrict__ W2,
                        float* __restrict__ d1, float* __restrict__ d2) {
    int b = blockIdx.x;
    int t = threadIdx.x;
    __shared__ float sh1[CIN];
    __shared__ float sh2[F];
    if (t < CIN) sh1[t] = s1[b * CIN + t];
    if (t < F) sh2[t] = s2[b * F + t];
    __syncthreads();
    if (t < F) {
        float acc = 0.f;
        const float* w = W1 + (size_t)t * CIN * 3;
        for (int c = 0; c < CIN; ++c) {
            float s = sh1[c];
            float w0 = w[c * 3], w1 = w[c * 3 + 1], w2 = w[c * 3 + 2];
            acc += s * s * (w0 * w0 + w1 * w1 + w2 * w2);
        }
        d1[b * F + t] = rsqrtf(acc + EPS);
    } else {
        int f = t - F;
        float acc = 0.f;
        const float* w = W2 + (size_t)f * F * 3;
        for (int c = 0; c < F; ++c) {
            float s = sh2[c];
            float w0 = w[c * 3], w1 = w[c * 3 + 1], w2 = w[c * 3 + 2];
            acc += s * s * (w0 * w0 + w1 * w1 + w2 * w2);
        }
        d2[b * F + f] = rsqrtf(acc + EPS);
    }
}

// ---------------- prep: W -> bf16 [kk][f][c] ----------------
__global__ void k_prepw(const float* __restrict__ W1, const float* __restrict__ W2,
                        unsigned short* __restrict__ Wt1, unsigned short* __restrict__ Wt2) {
    int i = blockIdx.x * 256 + threadIdx.x;
    if (i < 3 * F * CIN) {
        int kk = i / (F * CIN);
        int rem = i - kk * (F * CIN);
        int f = rem >> 8, c = rem & 255;
        Wt1[i] = f2bf(W1[(f * CIN + c) * 3 + kk]);
    }
    if (i < 3 * F * F) {
        int kk = i / (F * F);
        int rem = i - kk * (F * F);
        int f = rem >> 7, c = rem & 127;
        Wt2[i] = f2bf(W2[(f * F + c) * 3 + kk]);
    }
}

// ---------------- prep: xt[b][l][c] = upsample(x)*s1, bf16 (parked in d_out) ----------
__global__ __launch_bounds__(256) void k_prepx(const float* __restrict__ x,
                                               const float* __restrict__ s1,
                                               unsigned short* __restrict__ xt) {
    int b = blockIdx.z, c0 = blockIdx.y * 64, l0 = blockIdx.x * 64;
    int t = threadIdx.x;
    __shared__ float xj[64][37];
    int j0 = (l0 >> 1) - 1;
    for (int idx = t; idx < 64 * 34; idx += 256) {
        int c = idx / 34, jj = idx - c * 34;
        int j = j0 + jj;
        j = j < 0 ? 0 : (j > L - 1 ? L - 1 : j);
        xj[c][jj] = x[((size_t)(b * CIN + c0 + c)) * L + j];
    }
    __syncthreads();
    int c = t & 63;
    int lg = t >> 6;
    float s = s1[b * CIN + c0 + c];
    for (int li = 0; li < 16; ++li) {
        int ll = lg * 16 + li;
        int l = l0 + ll;
        int j = l >> 1;
        int jj = j - j0;
        float v;
        if (l & 1) {
            v = 0.75f * xj[c][jj] + 0.25f * xj[c][jj + 1];
        } else {
            v = (j == 0) ? xj[c][jj] : (0.25f * xj[c][jj - 1] + 0.75f * xj[c][jj]);
        }
        xt[((size_t)(b * LU + l)) * CIN + c0 + c] = f2bf(v * s);
    }
}

// ---------------- conv1 MFMA (no LDS): y1[b][l][f] bf16 = demod(conv(xt, W1)) ---------
__global__ __launch_bounds__(256) void k_conv1(const unsigned short* __restrict__ xt,
                                               const unsigned short* __restrict__ Wt1,
                                               const float* __restrict__ d1,
                                               unsigned short* __restrict__ y1) {
    const int b = blockIdx.y;
    const int l0 = blockIdx.x * 64;
    const int lane = threadIdx.x & 63, wv = threadIdx.x >> 6;
    const int lbase = l0 + wv * 16;
    const int m = lane & 15, ks = lane >> 4;  // frag row / k-slot

    f32x4 acc[8];
#pragma unroll
    for (int nf = 0; nf < 8; ++nf) acc[nf] = (f32x4)0.f;

    const unsigned short* xb = xt + ((size_t)b * LU) * CIN + ks * 8;

#pragma unroll 2
    for (int kc = 0; kc < 8; ++kc) {  // channel chunk: c0 = kc*32
#pragma unroll
        for (int kk = 0; kk < 3; ++kk) {  // conv tap
            int lA = lbase + m + kk - 1;
            bf16x8 a = (bf16x8)0;
            if (lA >= 0 && lA < LU)
                a = *(const bf16x8*)&xb[(size_t)lA * CIN + kc * 32];
#pragma unroll
            for (int nf = 0; nf < 8; ++nf) {
                const bf16x8 w =
                    *(const bf16x8*)&Wt1[((kk * F + nf * 16 + m) << 8) + kc * 32 + ks * 8];
                acc[nf] = __builtin_amdgcn_mfma_f32_16x16x32_bf16(a, w, acc[nf], 0, 0, 0);
            }
        }
    }
#pragma unroll
    for (int nf = 0; nf < 8; ++nf) {
        int f = nf * 16 + m;  // C col = lane&15 -> N = f
        float dm = d1[b * F + f];
#pragma unroll
        for (int q = 0; q < 4; ++q) {
            int l = lbase + ks * 4 + q;  // C row = (lane>>4)*4+q -> M = l
            y1[((size_t)(b * LU + l) << 7) + f] = f2bf(acc[nf][q] * dm);
        }
    }
}

// ---------------- noise1 (IN-PLACE): y1 = lrelu(y1 + inoise@nw1.T) * s2 ---------------
// s2 folded here so conv2's input is pre-modulated (mod_conv1d scales input by s2).
__global__ __launch_bounds__(256) void k_noise1(unsigned short* y1,
                                                const float* __restrict__ nw,
                                                const float* __restrict__ inoise,
                                                const float* __restrict__ s2) {
    int t = threadIdx.x;
    __shared__ float ns[B][NZ];
    __shared__ float s2s[B][F];
    for (int idx = t; idx < B * NZ; idx += 256) ns[idx / NZ][idx % NZ] = inoise[idx];
    for (int idx = t; idx < B * F; idx += 256) s2s[idx >> 7][idx & 127] = s2[idx];
    __syncthreads();
    int i = blockIdx.x * 256 + t;  // (l,f): l=i>>7, f=i&127
    int l = i >> 7, f = i & 127;
    const float* row = nw + (size_t)(f * LU + l) * NZ;
    float acc[B];
#pragma unroll
    for (int bb = 0; bb < B; ++bb) acc[bb] = 0.f;
    for (int z = 0; z < NZ; z += 4) {
        float4 w = *(const float4*)(row + z);
#pragma unroll
        for (int bb = 0; bb < B; ++bb) {
            acc[bb] += w.x * ns[bb][z] + w.y * ns[bb][z + 1] +
                       w.z * ns[bb][z + 2] + w.w * ns[bb][z + 3];
        }
    }
#pragma unroll
    for (int bb = 0; bb < B; ++bb) {
        float v = bf2f(y1[(size_t)bb * S + i]) + acc[bb];
        v = v >= 0.f ? v : LEAK * v;
        y1[(size_t)bb * S + i] = f2bf(v * s2s[bb][f]);
    }
}

// ---------------- conv2 MFMA (no LDS): xout[b][f][l] f32 = demod(conv(y1, W2)) --------
__global__ __launch_bounds__(256) void k_conv2(const unsigned short* __restrict__ y1n,
                                               const unsigned short* __restrict__ Wt2,
                                               const float* __restrict__ d2,
                                               float* __restrict__ xout) {
    const int b = blockIdx.y;
    const int l0 = blockIdx.x * 64;
    const int lane = threadIdx.x & 63, wv = threadIdx.x >> 6;
    const int lbase = l0 + wv * 16;
    const int m = lane & 15, ks = lane >> 4;

    f32x4 acc[8];
#pragma unroll
    for (int mf = 0; mf < 8; ++mf) acc[mf] = (f32x4)0.f;

    const unsigned short* yb = y1n + ((size_t)b * LU) * F + ks * 8;

#pragma unroll 2
    for (int kc = 0; kc < 4; ++kc) {  // channel chunk: c0 = kc*32
#pragma unroll
        for (int kk = 0; kk < 3; ++kk) {
            int lB = lbase + m + kk - 1;  // B col = lane&15 -> N = l
            bf16x8 bv = (bf16x8)0;
            if (lB >= 0 && lB < LU)
                bv = *(const bf16x8*)&yb[(size_t)lB * F + kc * 32];
#pragma unroll
            for (int mf = 0; mf < 8; ++mf) {
                const bf16x8 w =
                    *(const bf16x8*)&Wt2[((kk * F + mf * 16 + m) << 7) + kc * 32 + ks * 8];
                acc[mf] = __builtin_amdgcn_mfma_f32_16x16x32_bf16(w, bv, acc[mf], 0, 0, 0);
            }
        }
    }
#pragma unroll
    for (int mf = 0; mf < 8; ++mf) {
#pragma unroll
        for (int q = 0; q < 4; ++q) {
            int f = mf * 16 + ks * 4 + q;  // C row -> M = f
            int l = lbase + m;             // C col -> N = l
            xout[((size_t)(b * F + f) << 12) + l] = acc[mf][q] * d2[b * F + f];
        }
    }
}

// ---------------- noise2: xio = lrelu(xio + inoise@nw2.T), in place on d_out ----------
__global__ __launch_bounds__(256) void k_noise2(const float* __restrict__ nw,
                                                const float* __restrict__ inoise,
                                                float* xio) {
    int t = threadIdx.x;
    __shared__ float ns[B][NZ];
    for (int idx = t; idx < B * NZ; idx += 256) ns[idx / NZ][idx % NZ] = inoise[idx];
    __syncthreads();
    int i = blockIdx.x * 256 + t;  // = f*LU + l
    const float* row = nw + (size_t)i * NZ;
    float acc[B];
#pragma unroll
    for (int bb = 0; bb < B; ++bb) acc[bb] = 0.f;
    for (int z = 0; z < NZ; z += 4) {
        float4 w = *(const float4*)(row + z);
#pragma unroll
        for (int bb = 0; bb < B; ++bb) {
            acc[bb] += w.x * ns[bb][z] + w.y * ns[bb][z + 1] +
                       w.z * ns[bb][z + 2] + w.w * ns[bb][z + 3];
        }
    }
#pragma unroll
    for (int bb = 0; bb < B; ++bb) {
        float v = xio[(size_t)bb * S + i] + acc[bb];
        v = v >= 0.f ? v : LEAK * v;
        xio[(size_t)bb * S + i] = v;
    }
}

// ---------------- rgb ----------------
__global__ void k_rgb1(const float* __restrict__ xf, const float* __restrict__ srgbS,
                       const float* __restrict__ prev, float* __restrict__ rgb_pre) {
    int b = blockIdx.y;
    int l = blockIdx.x * 256 + threadIdx.x;
    __shared__ float ss[F];
    if (threadIdx.x < F) ss[threadIdx.x] = srgbS[b * F + threadIdx.x];
    __syncthreads();
    float acc = prev[b * LU + l];
    const float* xb = xf + (size_t)b * S + l;
    for (int f = 0; f < F; ++f) acc += xb[(size_t)f * LU] * ss[f];
    rgb_pre[b * LU + l] = acc;
}

__global__ void k_rgb2(const float* __restrict__ rgb_pre, float* __restrict__ rgb) {
    int i = blockIdx.x * 256 + threadIdx.x;
    int b = i >> 13;
    int lo = i & 8191;
    const float* r = rgb_pre + b * LU;
    float v;
    int j = lo >> 1;
    if (lo & 1) {
        int j1 = (j + 1 < LU) ? j + 1 : LU - 1;
        v = 0.75f * r[j] + 0.25f * r[j1];
    } else {
        v = (j == 0) ? r[0] : (0.25f * r[j - 1] + 0.75f * r[j]);
    }
    rgb[i] = v;
}

extern "C" void kernel_launch(void* const* d_in, const int* in_sizes, int n_in,
                              void* d_out, int out_size, void* d_ws, size_t ws_size,
                              hipStream_t stream) {
    const float* x      = (const float*)d_in[0];
    const float* prev   = (const float*)d_in[1];
    const float* istyle = (const float*)d_in[2];
    const float* inoise = (const float*)d_in[3];
    const float* s1w    = (const float*)d_in[4];
    const float* s1b    = (const float*)d_in[5];
    const float* W1     = (const float*)d_in[6];
    const float* nw1    = (const float*)d_in[7];
    const float* s2w    = (const float*)d_in[8];
    const float* s2b    = (const float*)d_in[9];
    const float* W2     = (const float*)d_in[10];
    const float* nw2    = (const float*)d_in[11];
    const float* rgbw   = (const float*)d_in[12];
    const float* rgbb   = (const float*)d_in[13];
    const float* rgbcw  = (const float*)d_in[14];

    // ---- workspace: total 9 MB (round-0 proved ws_size >= ~16.2 MB) ----
    char* w = (char*)d_ws;
    float* s1      = (float*)(w);                             // 8 KB
    float* s2      = (float*)(w + 8 * 1024);                  // 4 KB
    float* srgbS   = (float*)(w + 12 * 1024);                 // 4 KB
    float* d1      = (float*)(w + 16 * 1024);                 // 4 KB
    float* d2      = (float*)(w + 20 * 1024);                 // 4 KB
    float* rgb_pre = (float*)(w + 24 * 1024);                 // 128 KB
    unsigned short* Wt1 = (unsigned short*)(w + 256 * 1024);  // 192 KB
    unsigned short* Wt2 = (unsigned short*)(w + 448 * 1024);  // 96 KB
    unsigned short* y1  = (unsigned short*)(w + (size_t)1024 * 1024);  // 8 MB

    // xt (16 MB bf16) parked in d_out (17.04 MB): dead once conv2 writes xout.
    unsigned short* xt = (unsigned short*)d_out;

    float* xout   = (float*)d_out;
    float* rgbout = xout + (size_t)B * S;

    k_styles<<<8, 256, 0, stream>>>(istyle, s1w, s1b, s2w, s2b, rgbw, rgbb, rgbcw,
                                    s1, s2, srgbS);
    k_demod<<<8, 256, 0, stream>>>(s1, s2, W1, W2, d1, d2);
    k_prepw<<<(3 * F * CIN) / 256, 256, 0, stream>>>(W1, W2, Wt1, Wt2);
    k_prepx<<<dim3(LU / 64, CIN / 64, B), 256, 0, stream>>>(x, s1, xt);
    k_conv1<<<dim3(LU / 64, B), 256, 0, stream>>>(xt, Wt1, d1, y1);
    k_noise1<<<S / 256, 256, 0, stream>>>(y1, nw1, inoise, s2);
    k_conv2<<<dim3(LU / 64, B), 256, 0, stream>>>(y1, Wt2, d2, xout);
    k_noise2<<<S / 256, 256, 0, stream>>>(nw2, inoise, xout);
    k_rgb1<<<dim3(LU / 256, B), 256, 0, stream>>>(xout, srgbS, prev, rgb_pre);
    k_rgb2<<<B * 2 * LU / 256, 256, 0, stream>>>(rgb_pre, rgbout);
}

// Round 6
// 290.317 us; speedup vs baseline: 1.6903x; 1.0749x over previous
//
#include <hip/hip_runtime.h>

#define EPS 1e-8f
#define LEAK 0.2f

#define B 8
#define CIN 256
#define F 128
#define L 2048
#define LU 4096
#define Z 256
#define NZ 100
#define S (F * LU)

typedef __attribute__((ext_vector_type(8))) short bf16x8;
typedef __attribute__((ext_vector_type(4))) float f32x4;

__device__ inline unsigned short f2bf(float x) {
    unsigned u = __builtin_bit_cast(unsigned, x);
    u += 0x7fffu + ((u >> 16) & 1u);
    return (unsigned short)(u >> 16);
}
__device__ inline float bf2f(unsigned short h) {
    unsigned u = ((unsigned)h) << 16;
    return __builtin_bit_cast(float, u);
}

// ---------------- styles + demod fused ----------------
__global__ void k_styles(const float* __restrict__ istyle,
                         const float* __restrict__ s1w, const float* __restrict__ s1b,
                         const float* __restrict__ s2w, const float* __restrict__ s2b,
                         const float* __restrict__ rgbw, const float* __restrict__ rgbb,
                         const float* __restrict__ rgbcw,
                         const float* __restrict__ W1, const float* __restrict__ W2,
                         float* __restrict__ s1, float* __restrict__ s2,
                         float* __restrict__ srgbS,
                         float* __restrict__ d1, float* __restrict__ d2) {
    __shared__ float is[Z];
    __shared__ float sh1[CIN];
    __shared__ float sh2[F];
    int b = blockIdx.x;
    int t = threadIdx.x;
    if (t < Z) is[t] = istyle[b * Z + t];
    __syncthreads();
    {
        float acc = 0.f;
        const float* w = s1w + (size_t)t * Z;
        for (int z = 0; z < Z; ++z) acc += is[z] * w[z];
        float v = acc + s1b[t] + 1.0f;
        sh1[t] = v;
        s1[b * CIN + t] = v;
    }
    if (t < F) {
        float a2 = 0.f, a3 = 0.f;
        const float* w2 = s2w + (size_t)t * Z;
        const float* w3 = rgbw + (size_t)t * Z;
        for (int z = 0; z < Z; ++z) { a2 += is[z] * w2[z]; a3 += is[z] * w3[z]; }
        float v2 = a2 + s2b[t] + 1.0f;
        sh2[t] = v2;
        s2[b * F + t] = v2;
        srgbS[b * F + t] = (a3 + rgbb[t] + 1.0f) * rgbcw[t];
    }
    __syncthreads();
    // demod
    if (t < F) {
        float acc = 0.f;
        const float* w = W1 + (size_t)t * CIN * 3;
        for (int c = 0; c < CIN; ++c) {
            float s = sh1[c];
            float w0 = w[c * 3], w1 = w[c * 3 + 1], w2 = w[c * 3 + 2];
            acc += s * s * (w0 * w0 + w1 * w1 + w2 * w2);
        }
        d1[b * F + t] = rsqrtf(acc + EPS);
    } else {
        int f = t - F;
        float acc = 0.f;
        const float* w = W2 + (size_t)f * F * 3;
        for (int c = 0; c < F; ++c) {
            float s = sh2[c];
            float w0 = w[c * 3], w1 = w[c * 3 + 1], w2 = w[c * 3 + 2];
            acc += s * s * (w0 * w0 + w1 * w1 + w2 * w2);
        }
        d2[b * F + f] = rsqrtf(acc + EPS);
    }
}

// ---------------- prep: W -> bf16 [kk][f][c] ----------------
__global__ void k_prepw(const float* __restrict__ W1, const float* __restrict__ W2,
                        unsigned short* __restrict__ Wt1, unsigned short* __restrict__ Wt2) {
    int i = blockIdx.x * 256 + threadIdx.x;
    if (i < 3 * F * CIN) {
        int kk = i / (F * CIN);
        int rem = i - kk * (F * CIN);
        int f = rem >> 8, c = rem & 255;
        Wt1[i] = f2bf(W1[(f * CIN + c) * 3 + kk]);
    }
    if (i < 3 * F * F) {
        int kk = i / (F * F);
        int rem = i - kk * (F * F);
        int f = rem >> 7, c = rem & 127;
        Wt2[i] = f2bf(W2[(f * F + c) * 3 + kk]);
    }
}

// ---------------- prep: xt[b][l][c] = upsample(x)*s1, bf16 (parked in d_out) ----------
__global__ __launch_bounds__(256) void k_prepx(const float* __restrict__ x,
                                               const float* __restrict__ s1,
                                               unsigned short* __restrict__ xt) {
    int b = blockIdx.z, c0 = blockIdx.y * 64, l0 = blockIdx.x * 64;
    int t = threadIdx.x;
    __shared__ float xj[64][37];
    int j0 = (l0 >> 1) - 1;
    for (int idx = t; idx < 64 * 34; idx += 256) {
        int c = idx / 34, jj = idx - c * 34;
        int j = j0 + jj;
        j = j < 0 ? 0 : (j > L - 1 ? L - 1 : j);
        xj[c][jj] = x[((size_t)(b * CIN + c0 + c)) * L + j];
    }
    __syncthreads();
    int c = t & 63;
    int lg = t >> 6;
    float s = s1[b * CIN + c0 + c];
    for (int li = 0; li < 16; ++li) {
        int ll = lg * 16 + li;
        int l = l0 + ll;
        int j = l >> 1;
        int jj = j - j0;
        float v;
        if (l & 1) {
            v = 0.75f * xj[c][jj] + 0.25f * xj[c][jj + 1];
        } else {
            v = (j == 0) ? xj[c][jj] : (0.25f * xj[c][jj - 1] + 0.75f * xj[c][jj]);
        }
        xt[((size_t)(b * LU + l)) * CIN + c0 + c] = f2bf(v * s);
    }
}

// ---------------- conv1 MFMA: y1[b][l][f] bf16 = demod(conv(xt, W1)) ------------------
// f-split x2, batch-pair: weight fragment loaded once, used for 2 batches.
__global__ __launch_bounds__(256) void k_conv1(const unsigned short* __restrict__ xt,
                                               const unsigned short* __restrict__ Wt1,
                                               const float* __restrict__ d1,
                                               unsigned short* __restrict__ y1) {
    const int b0 = blockIdx.y * 2;
    const int l0 = blockIdx.x * 64;
    const int nfb = blockIdx.z * 4;  // f fragment base
    const int lane = threadIdx.x & 63, wv = threadIdx.x >> 6;
    const int lbase = l0 + wv * 16;
    const int m = lane & 15, ks = lane >> 4;  // frag row / k-slot

    f32x4 acc[2][4];
#pragma unroll
    for (int bb = 0; bb < 2; ++bb)
#pragma unroll
        for (int nf = 0; nf < 4; ++nf) acc[bb][nf] = (f32x4)0.f;

    const unsigned short* xb0 = xt + ((size_t)(b0 + 0) * LU) * CIN + ks * 8;
    const unsigned short* xb1 = xt + ((size_t)(b0 + 1) * LU) * CIN + ks * 8;

#pragma unroll 2
    for (int kc = 0; kc < 8; ++kc) {  // channel chunk: c0 = kc*32
#pragma unroll
        for (int kk = 0; kk < 3; ++kk) {  // conv tap
            int lA = lbase + m + kk - 1;
            bf16x8 a0 = (bf16x8)0, a1 = (bf16x8)0;
            if (lA >= 0 && lA < LU) {
                a0 = *(const bf16x8*)&xb0[(size_t)lA * CIN + kc * 32];
                a1 = *(const bf16x8*)&xb1[(size_t)lA * CIN + kc * 32];
            }
#pragma unroll
            for (int nf = 0; nf < 4; ++nf) {
                const bf16x8 w =
                    *(const bf16x8*)&Wt1[((kk * F + (nfb + nf) * 16 + m) << 8) + kc * 32 + ks * 8];
                acc[0][nf] = __builtin_amdgcn_mfma_f32_16x16x32_bf16(a0, w, acc[0][nf], 0, 0, 0);
                acc[1][nf] = __builtin_amdgcn_mfma_f32_16x16x32_bf16(a1, w, acc[1][nf], 0, 0, 0);
            }
        }
    }
#pragma unroll
    for (int bb = 0; bb < 2; ++bb) {
        int b = b0 + bb;
#pragma unroll
        for (int nf = 0; nf < 4; ++nf) {
            int f = (nfb + nf) * 16 + m;  // C col = lane&15 -> N = f
            float dm = d1[b * F + f];
#pragma unroll
            for (int q = 0; q < 4; ++q) {
                int l = lbase + ks * 4 + q;  // C row = (lane>>4)*4+q -> M = l
                y1[((size_t)(b * LU + l) << 7) + f] = f2bf(acc[bb][nf][q] * dm);
            }
        }
    }
}

// ---------------- noise1 (IN-PLACE): y1 = lrelu(y1 + inoise@nw1.T) * s2 ---------------
__global__ __launch_bounds__(256) void k_noise1(unsigned short* y1,
                                                const float* __restrict__ nw,
                                                const float* __restrict__ inoise,
                                                const float* __restrict__ s2) {
    int t = threadIdx.x;
    __shared__ float ns[B][NZ];
    __shared__ float s2s[B][F];
    for (int idx = t; idx < B * NZ; idx += 256) ns[idx / NZ][idx % NZ] = inoise[idx];
    for (int idx = t; idx < B * F; idx += 256) s2s[idx >> 7][idx & 127] = s2[idx];
    __syncthreads();
    int i = blockIdx.x * 256 + t;  // (l,f): l=i>>7, f=i&127
    int l = i >> 7, f = i & 127;
    const float* row = nw + (size_t)(f * LU + l) * NZ;
    float acc[B];
#pragma unroll
    for (int bb = 0; bb < B; ++bb) acc[bb] = 0.f;
    for (int z = 0; z < NZ; z += 4) {
        float4 w = *(const float4*)(row + z);
#pragma unroll
        for (int bb = 0; bb < B; ++bb) {
            acc[bb] += w.x * ns[bb][z] + w.y * ns[bb][z + 1] +
                       w.z * ns[bb][z + 2] + w.w * ns[bb][z + 3];
        }
    }
#pragma unroll
    for (int bb = 0; bb < B; ++bb) {
        float v = bf2f(y1[(size_t)bb * S + i]) + acc[bb];
        v = v >= 0.f ? v : LEAK * v;
        y1[(size_t)bb * S + i] = f2bf(v * s2s[bb][f]);
    }
}

// ---------------- conv2 MFMA: xout[b][f][l] f32 = demod(conv(y1, W2)) -----------------
// f-split x2, batch-pair: weight fragment loaded once, used for 2 batches.
__global__ __launch_bounds__(256) void k_conv2(const unsigned short* __restrict__ y1n,
                                               const unsigned short* __restrict__ Wt2,
                                               const float* __restrict__ d2,
                                               float* __restrict__ xout) {
    const int b0 = blockIdx.y * 2;
    const int l0 = blockIdx.x * 64;
    const int mfb = blockIdx.z * 4;
    const int lane = threadIdx.x & 63, wv = threadIdx.x >> 6;
    const int lbase = l0 + wv * 16;
    const int m = lane & 15, ks = lane >> 4;

    f32x4 acc[2][4];
#pragma unroll
    for (int bb = 0; bb < 2; ++bb)
#pragma unroll
        for (int mf = 0; mf < 4; ++mf) acc[bb][mf] = (f32x4)0.f;

    const unsigned short* yb0 = y1n + ((size_t)(b0 + 0) * LU) * F + ks * 8;
    const unsigned short* yb1 = y1n + ((size_t)(b0 + 1) * LU) * F + ks * 8;

#pragma unroll 2
    for (int kc = 0; kc < 4; ++kc) {  // channel chunk: c0 = kc*32
#pragma unroll
        for (int kk = 0; kk < 3; ++kk) {
            int lB = lbase + m + kk - 1;  // B col = lane&15 -> N = l
            bf16x8 bv0 = (bf16x8)0, bv1 = (bf16x8)0;
            if (lB >= 0 && lB < LU) {
                bv0 = *(const bf16x8*)&yb0[(size_t)lB * F + kc * 32];
                bv1 = *(const bf16x8*)&yb1[(size_t)lB * F + kc * 32];
            }
#pragma unroll
            for (int mf = 0; mf < 4; ++mf) {
                const bf16x8 w =
                    *(const bf16x8*)&Wt2[((kk * F + (mfb + mf) * 16 + m) << 7) + kc * 32 + ks * 8];
                acc[0][mf] = __builtin_amdgcn_mfma_f32_16x16x32_bf16(w, bv0, acc[0][mf], 0, 0, 0);
                acc[1][mf] = __builtin_amdgcn_mfma_f32_16x16x32_bf16(w, bv1, acc[1][mf], 0, 0, 0);
            }
        }
    }
#pragma unroll
    for (int bb = 0; bb < 2; ++bb) {
        int b = b0 + bb;
#pragma unroll
        for (int mf = 0; mf < 4; ++mf) {
#pragma unroll
            for (int q = 0; q < 4; ++q) {
                int f = (mfb + mf) * 16 + ks * 4 + q;  // C row -> M = f
                int l = lbase + m;                     // C col -> N = l
                xout[((size_t)(b * F + f) << 12) + l] = acc[bb][mf][q] * d2[b * F + f];
            }
        }
    }
}

// ---------------- noise2: xio = lrelu(xio + inoise@nw2.T), in place on d_out ----------
__global__ __launch_bounds__(256) void k_noise2(const float* __restrict__ nw,
                                                const float* __restrict__ inoise,
                                                float* xio) {
    int t = threadIdx.x;
    __shared__ float ns[B][NZ];
    for (int idx = t; idx < B * NZ; idx += 256) ns[idx / NZ][idx % NZ] = inoise[idx];
    __syncthreads();
    int i = blockIdx.x * 256 + t;  // = f*LU + l
    const float* row = nw + (size_t)i * NZ;
    float acc[B];
#pragma unroll
    for (int bb = 0; bb < B; ++bb) acc[bb] = 0.f;
    for (int z = 0; z < NZ; z += 4) {
        float4 w = *(const float4*)(row + z);
#pragma unroll
        for (int bb = 0; bb < B; ++bb) {
            acc[bb] += w.x * ns[bb][z] + w.y * ns[bb][z + 1] +
                       w.z * ns[bb][z + 2] + w.w * ns[bb][z + 3];
        }
    }
#pragma unroll
    for (int bb = 0; bb < B; ++bb) {
        float v = xio[(size_t)bb * S + i] + acc[bb];
        v = v >= 0.f ? v : LEAK * v;
        xio[(size_t)bb * S + i] = v;
    }
}

// ---------------- rgb fused: reduce over f, add prev, upsample 2x ---------------------
// block: one b, 512 outputs [o0, o0+512). LDS holds pre[258] = rgb_pre[j0..j0+257].
__global__ __launch_bounds__(256) void k_rgb(const float* __restrict__ xf,
                                             const float* __restrict__ srgbS,
                                             const float* __restrict__ prev,
                                             float* __restrict__ rgb) {
    int b = blockIdx.y;
    int o0 = blockIdx.x * 512;
    int t = threadIdx.x;
    __shared__ float ss[F];
    __shared__ float pre[258];
    if (t < F) ss[t] = srgbS[b * F + t];
    __syncthreads();
    int j0 = (o0 >> 1) - 1;
    for (int jj = t; jj < 258; jj += 256) {
        int j = j0 + jj;
        j = j < 0 ? 0 : (j > LU - 1 ? LU - 1 : j);
        float acc = prev[b * LU + j];
        const float* xb = xf + (size_t)b * S + j;
        for (int f = 0; f < F; ++f) acc += xb[(size_t)f * LU] * ss[f];
        pre[jj] = acc;
    }
    __syncthreads();
    // outputs o = o0 + 2t (even), o0 + 2t + 1 (odd); j = o>>1 = o0/2 + t -> jj = t+1
    int jj = t + 1;
    int j = j0 + jj;
    float ve = (j == 0) ? pre[jj] : (0.25f * pre[jj - 1] + 0.75f * pre[jj]);
    float vo = 0.75f * pre[jj] + 0.25f * pre[jj + 1];
    float2 v2 = make_float2(ve, vo);
    *(float2*)&rgb[(size_t)b * 2 * LU + o0 + 2 * t] = v2;
}

extern "C" void kernel_launch(void* const* d_in, const int* in_sizes, int n_in,
                              void* d_out, int out_size, void* d_ws, size_t ws_size,
                              hipStream_t stream) {
    const float* x      = (const float*)d_in[0];
    const float* prev   = (const float*)d_in[1];
    const float* istyle = (const float*)d_in[2];
    const float* inoise = (const float*)d_in[3];
    const float* s1w    = (const float*)d_in[4];
    const float* s1b    = (const float*)d_in[5];
    const float* W1     = (const float*)d_in[6];
    const float* nw1    = (const float*)d_in[7];
    const float* s2w    = (const float*)d_in[8];
    const float* s2b    = (const float*)d_in[9];
    const float* W2     = (const float*)d_in[10];
    const float* nw2    = (const float*)d_in[11];
    const float* rgbw   = (const float*)d_in[12];
    const float* rgbb   = (const float*)d_in[13];
    const float* rgbcw  = (const float*)d_in[14];

    char* w = (char*)d_ws;
    float* s1      = (float*)(w);                             // 8 KB
    float* s2      = (float*)(w + 8 * 1024);                  // 4 KB
    float* srgbS   = (float*)(w + 12 * 1024);                 // 4 KB
    float* d1      = (float*)(w + 16 * 1024);                 // 4 KB
    float* d2      = (float*)(w + 20 * 1024);                 // 4 KB
    unsigned short* Wt1 = (unsigned short*)(w + 256 * 1024);  // 192 KB
    unsigned short* Wt2 = (unsigned short*)(w + 448 * 1024);  // 96 KB
    unsigned short* y1  = (unsigned short*)(w + (size_t)1024 * 1024);  // 8 MB

    // xt (16 MB bf16) parked in d_out: dead once conv2 starts writing xout there.
    unsigned short* xt = (unsigned short*)d_out;

    float* xout   = (float*)d_out;
    float* rgbout = xout + (size_t)B * S;

    k_styles<<<8, 256, 0, stream>>>(istyle, s1w, s1b, s2w, s2b, rgbw, rgbb, rgbcw,
                                    W1, W2, s1, s2, srgbS, d1, d2);
    k_prepw<<<(3 * F * CIN) / 256, 256, 0, stream>>>(W1, W2, Wt1, Wt2);
    k_prepx<<<dim3(LU / 64, CIN / 64, B), 256, 0, stream>>>(x, s1, xt);
    k_conv1<<<dim3(LU / 64, B / 2, 2), 256, 0, stream>>>(xt, Wt1, d1, y1);
    k_noise1<<<S / 256, 256, 0, stream>>>(y1, nw1, inoise, s2);
    k_conv2<<<dim3(LU / 64, B / 2, 2), 256, 0, stream>>>(y1, Wt2, d2, xout);
    k_noise2<<<S / 256, 256, 0, stream>>>(nw2, inoise, xout);
    k_rgb<<<dim3(2 * LU / 512, B), 256, 0, stream>>>(xout, srgbS, prev, rgbout);
}

// Round 8
// 273.648 us; speedup vs baseline: 1.7933x; 1.0609x over previous
//
#include <hip/hip_runtime.h>

#define EPS 1e-8f
#define LEAK 0.2f

#define B 8
#define CIN 256
#define F 128
#define L 2048
#define LU 4096
#define Z 256
#define NZ 100
#define S (F * LU)

typedef __attribute__((ext_vector_type(8))) short bf16x8;
typedef __attribute__((ext_vector_type(4))) float f32x4;

__device__ inline unsigned short f2bf(float x) {
    unsigned u = __builtin_bit_cast(unsigned, x);
    u += 0x7fffu + ((u >> 16) & 1u);
    return (unsigned short)(u >> 16);
}
__device__ inline float bf2f(unsigned short h) {
    unsigned u = ((unsigned)h) << 16;
    return __builtin_bit_cast(float, u);
}

// ---------------- styles + demod fused ----------------
__global__ void k_styles(const float* __restrict__ istyle,
                         const float* __restrict__ s1w, const float* __restrict__ s1b,
                         const float* __restrict__ s2w, const float* __restrict__ s2b,
                         const float* __restrict__ rgbw, const float* __restrict__ rgbb,
                         const float* __restrict__ rgbcw,
                         const float* __restrict__ W1, const float* __restrict__ W2,
                         float* __restrict__ s1, float* __restrict__ s2,
                         float* __restrict__ srgbS,
                         float* __restrict__ d1, float* __restrict__ d2) {
    __shared__ float is[Z];
    __shared__ float sh1[CIN];
    __shared__ float sh2[F];
    int b = blockIdx.x;
    int t = threadIdx.x;
    if (t < Z) is[t] = istyle[b * Z + t];
    __syncthreads();
    {
        float acc = 0.f;
        const float* w = s1w + (size_t)t * Z;
        for (int z = 0; z < Z; ++z) acc += is[z] * w[z];
        float v = acc + s1b[t] + 1.0f;
        sh1[t] = v;
        s1[b * CIN + t] = v;
    }
    if (t < F) {
        float a2 = 0.f, a3 = 0.f;
        const float* w2 = s2w + (size_t)t * Z;
        const float* w3 = rgbw + (size_t)t * Z;
        for (int z = 0; z < Z; ++z) { a2 += is[z] * w2[z]; a3 += is[z] * w3[z]; }
        float v2 = a2 + s2b[t] + 1.0f;
        sh2[t] = v2;
        s2[b * F + t] = v2;
        srgbS[b * F + t] = (a3 + rgbb[t] + 1.0f) * rgbcw[t];
    }
    __syncthreads();
    if (t < F) {
        float acc = 0.f;
        const float* w = W1 + (size_t)t * CIN * 3;
        for (int c = 0; c < CIN; ++c) {
            float s = sh1[c];
            float w0 = w[c * 3], w1 = w[c * 3 + 1], w2 = w[c * 3 + 2];
            acc += s * s * (w0 * w0 + w1 * w1 + w2 * w2);
        }
        d1[b * F + t] = rsqrtf(acc + EPS);
    } else {
        int f = t - F;
        float acc = 0.f;
        const float* w = W2 + (size_t)f * F * 3;
        for (int c = 0; c < F; ++c) {
            float s = sh2[c];
            float w0 = w[c * 3], w1 = w[c * 3 + 1], w2 = w[c * 3 + 2];
            acc += s * s * (w0 * w0 + w1 * w1 + w2 * w2);
        }
        d2[b * F + f] = rsqrtf(acc + EPS);
    }
}

// ---------------- prep: W -> bf16 [kk][f][c] ----------------
__global__ void k_prepw(const float* __restrict__ W1, const float* __restrict__ W2,
                        unsigned short* __restrict__ Wt1, unsigned short* __restrict__ Wt2) {
    int i = blockIdx.x * 256 + threadIdx.x;
    if (i < 3 * F * CIN) {
        int kk = i / (F * CIN);
        int rem = i - kk * (F * CIN);
        int f = rem >> 8, c = rem & 255;
        Wt1[i] = f2bf(W1[(f * CIN + c) * 3 + kk]);
    }
    if (i < 3 * F * F) {
        int kk = i / (F * F);
        int rem = i - kk * (F * F);
        int f = rem >> 7, c = rem & 127;
        Wt2[i] = f2bf(W2[(f * F + c) * 3 + kk]);
    }
}

// ---------------- prep: xt[b][l][c] = upsample(x)*s1, bf16 (parked in d_out) ----------
__global__ __launch_bounds__(256) void k_prepx(const float* __restrict__ x,
                                               const float* __restrict__ s1,
                                               unsigned short* __restrict__ xt) {
    int b = blockIdx.z, c0 = blockIdx.y * 64, l0 = blockIdx.x * 64;
    int t = threadIdx.x;
    __shared__ float xj[64][37];
    int j0 = (l0 >> 1) - 1;
    for (int idx = t; idx < 64 * 34; idx += 256) {
        int c = idx / 34, jj = idx - c * 34;
        int j = j0 + jj;
        j = j < 0 ? 0 : (j > L - 1 ? L - 1 : j);
        xj[c][jj] = x[((size_t)(b * CIN + c0 + c)) * L + j];
    }
    __syncthreads();
    int c = t & 63;
    int lg = t >> 6;
    float s = s1[b * CIN + c0 + c];
    for (int li = 0; li < 16; ++li) {
        int ll = lg * 16 + li;
        int l = l0 + ll;
        int j = l >> 1;
        int jj = j - j0;
        float v;
        if (l & 1) {
            v = 0.75f * xj[c][jj] + 0.25f * xj[c][jj + 1];
        } else {
            v = (j == 0) ? xj[c][jj] : (0.25f * xj[c][jj - 1] + 0.75f * xj[c][jj]);
        }
        xt[((size_t)(b * LU + l)) * CIN + c0 + c] = f2bf(v * s);
    }
}

// ---------------- conv1 MFMA: y1[b][l][f] bf16 = demod(conv(xt, W1)) ------------------
__global__ __launch_bounds__(256) void k_conv1(const unsigned short* __restrict__ xt,
                                               const unsigned short* __restrict__ Wt1,
                                               const float* __restrict__ d1,
                                               unsigned short* __restrict__ y1) {
    const int b0 = blockIdx.y * 2;
    const int l0 = blockIdx.x * 64;
    const int nfb = blockIdx.z * 4;
    const int lane = threadIdx.x & 63, wv = threadIdx.x >> 6;
    const int lbase = l0 + wv * 16;
    const int m = lane & 15, ks = lane >> 4;

    f32x4 acc[2][4];
#pragma unroll
    for (int bb = 0; bb < 2; ++bb)
#pragma unroll
        for (int nf = 0; nf < 4; ++nf) acc[bb][nf] = (f32x4)0.f;

    const unsigned short* xb0 = xt + ((size_t)(b0 + 0) * LU) * CIN + ks * 8;
    const unsigned short* xb1 = xt + ((size_t)(b0 + 1) * LU) * CIN + ks * 8;

#pragma unroll 2
    for (int kc = 0; kc < 8; ++kc) {
#pragma unroll
        for (int kk = 0; kk < 3; ++kk) {
            int lA = lbase + m + kk - 1;
            bf16x8 a0 = (bf16x8)0, a1 = (bf16x8)0;
            if (lA >= 0 && lA < LU) {
                a0 = *(const bf16x8*)&xb0[(size_t)lA * CIN + kc * 32];
                a1 = *(const bf16x8*)&xb1[(size_t)lA * CIN + kc * 32];
            }
#pragma unroll
            for (int nf = 0; nf < 4; ++nf) {
                const bf16x8 w =
                    *(const bf16x8*)&Wt1[((kk * F + (nfb + nf) * 16 + m) << 8) + kc * 32 + ks * 8];
                acc[0][nf] = __builtin_amdgcn_mfma_f32_16x16x32_bf16(a0, w, acc[0][nf], 0, 0, 0);
                acc[1][nf] = __builtin_amdgcn_mfma_f32_16x16x32_bf16(a1, w, acc[1][nf], 0, 0, 0);
            }
        }
    }
#pragma unroll
    for (int bb = 0; bb < 2; ++bb) {
        int b = b0 + bb;
#pragma unroll
        for (int nf = 0; nf < 4; ++nf) {
            int f = (nfb + nf) * 16 + m;
            float dm = d1[b * F + f];
#pragma unroll
            for (int q = 0; q < 4; ++q) {
                int l = lbase + ks * 4 + q;
                y1[((size_t)(b * LU + l) << 7) + f] = f2bf(acc[bb][nf][q] * dm);
            }
        }
    }
}

// ---------------- noise1 (IN-PLACE): y1 = lrelu(y1 + n1) * s2 -------------------------
// y1 index i = l*F + f; nw row = f*LU + l (reshape target is [B,F,Lu]!).
// z-chunked 128B visits (full-line consumption); inoise via uniform scalar loads.
__global__ __launch_bounds__(256) void k_noise1(unsigned short* y1,
                                                const float* __restrict__ nw,
                                                const float* __restrict__ inoise,
                                                const float* __restrict__ s2) {
    int t = threadIdx.x;
    int i = blockIdx.x * 256 + t;  // (l,f): l=i>>7, f=i&127
    int l = i >> 7, f = i & 127;
    const float* row = nw + (size_t)(f * LU + l) * NZ;
    float acc[B];
#pragma unroll
    for (int bb = 0; bb < B; ++bb) acc[bb] = 0.f;
#pragma unroll
    for (int zc = 0; zc < 96; zc += 32) {
        float4 v[8];
#pragma unroll
        for (int u = 0; u < 8; ++u) v[u] = *(const float4*)(row + zc + 4 * u);
#pragma unroll
        for (int u = 0; u < 8; ++u) {
            int z = zc + 4 * u;
#pragma unroll
            for (int bb = 0; bb < B; ++bb) {
                acc[bb] += v[u].x * inoise[bb * NZ + z] + v[u].y * inoise[bb * NZ + z + 1] +
                           v[u].z * inoise[bb * NZ + z + 2] + v[u].w * inoise[bb * NZ + z + 3];
            }
        }
    }
    {
        float4 v = *(const float4*)(row + 96);
#pragma unroll
        for (int bb = 0; bb < B; ++bb) {
            acc[bb] += v.x * inoise[bb * NZ + 96] + v.y * inoise[bb * NZ + 97] +
                       v.z * inoise[bb * NZ + 98] + v.w * inoise[bb * NZ + 99];
        }
    }
#pragma unroll
    for (int bb = 0; bb < B; ++bb) {
        float val = bf2f(y1[(size_t)bb * S + i]) + acc[bb];
        val = val >= 0.f ? val : LEAK * val;
        y1[(size_t)bb * S + i] = f2bf(val * s2[bb * F + f]);
    }
}

// ---------------- conv2 MFMA: xout[b][f][l] f32 = demod(conv(y1, W2)) -----------------
__global__ __launch_bounds__(256) void k_conv2(const unsigned short* __restrict__ y1n,
                                               const unsigned short* __restrict__ Wt2,
                                               const float* __restrict__ d2,
                                               float* __restrict__ xout) {
    const int b0 = blockIdx.y * 2;
    const int l0 = blockIdx.x * 64;
    const int mfb = blockIdx.z * 4;
    const int lane = threadIdx.x & 63, wv = threadIdx.x >> 6;
    const int lbase = l0 + wv * 16;
    const int m = lane & 15, ks = lane >> 4;

    f32x4 acc[2][4];
#pragma unroll
    for (int bb = 0; bb < 2; ++bb)
#pragma unroll
        for (int mf = 0; mf < 4; ++mf) acc[bb][mf] = (f32x4)0.f;

    const unsigned short* yb0 = y1n + ((size_t)(b0 + 0) * LU) * F + ks * 8;
    const unsigned short* yb1 = y1n + ((size_t)(b0 + 1) * LU) * F + ks * 8;

#pragma unroll 2
    for (int kc = 0; kc < 4; ++kc) {
#pragma unroll
        for (int kk = 0; kk < 3; ++kk) {
            int lB = lbase + m + kk - 1;
            bf16x8 bv0 = (bf16x8)0, bv1 = (bf16x8)0;
            if (lB >= 0 && lB < LU) {
                bv0 = *(const bf16x8*)&yb0[(size_t)lB * F + kc * 32];
                bv1 = *(const bf16x8*)&yb1[(size_t)lB * F + kc * 32];
            }
#pragma unroll
            for (int mf = 0; mf < 4; ++mf) {
                const bf16x8 w =
                    *(const bf16x8*)&Wt2[((kk * F + (mfb + mf) * 16 + m) << 7) + kc * 32 + ks * 8];
                acc[0][mf] = __builtin_amdgcn_mfma_f32_16x16x32_bf16(w, bv0, acc[0][mf], 0, 0, 0);
                acc[1][mf] = __builtin_amdgcn_mfma_f32_16x16x32_bf16(w, bv1, acc[1][mf], 0, 0, 0);
            }
        }
    }
#pragma unroll
    for (int bb = 0; bb < 2; ++bb) {
        int b = b0 + bb;
#pragma unroll
        for (int mf = 0; mf < 4; ++mf) {
#pragma unroll
            for (int q = 0; q < 4; ++q) {
                int f = (mfb + mf) * 16 + ks * 4 + q;
                int l = lbase + m;
                xout[((size_t)(b * F + f) << 12) + l] = acc[bb][mf][q] * d2[b * F + f];
            }
        }
    }
}

// ---------------- noise2 (IN-PLACE on d_out): x = lrelu(x + n2) -----------------------
// x index i = f*LU + l; nw row = i (identity). Same chunked + scalar-load scheme.
__global__ __launch_bounds__(256) void k_noise2(const float* __restrict__ nw,
                                                const float* __restrict__ inoise,
                                                float* xio) {
    int t = threadIdx.x;
    int i = blockIdx.x * 256 + t;  // = f*LU + l
    const float* row = nw + (size_t)i * NZ;
    float acc[B];
#pragma unroll
    for (int bb = 0; bb < B; ++bb) acc[bb] = 0.f;
#pragma unroll
    for (int zc = 0; zc < 96; zc += 32) {
        float4 v[8];
#pragma unroll
        for (int u = 0; u < 8; ++u) v[u] = *(const float4*)(row + zc + 4 * u);
#pragma unroll
        for (int u = 0; u < 8; ++u) {
            int z = zc + 4 * u;
#pragma unroll
            for (int bb = 0; bb < B; ++bb) {
                acc[bb] += v[u].x * inoise[bb * NZ + z] + v[u].y * inoise[bb * NZ + z + 1] +
                           v[u].z * inoise[bb * NZ + z + 2] + v[u].w * inoise[bb * NZ + z + 3];
            }
        }
    }
    {
        float4 v = *(const float4*)(row + 96);
#pragma unroll
        for (int bb = 0; bb < B; ++bb) {
            acc[bb] += v.x * inoise[bb * NZ + 96] + v.y * inoise[bb * NZ + 97] +
                       v.z * inoise[bb * NZ + 98] + v.w * inoise[bb * NZ + 99];
        }
    }
#pragma unroll
    for (int bb = 0; bb < B; ++bb) {
        float val = xio[(size_t)bb * S + i] + acc[bb];
        val = val >= 0.f ? val : LEAK * val;
        xio[(size_t)bb * S + i] = val;
    }
}

// ---------------- rgb fused: reduce over f, add prev, upsample 2x ---------------------
__global__ __launch_bounds__(256) void k_rgb(const float* __restrict__ xf,
                                             const float* __restrict__ srgbS,
                                             const float* __restrict__ prev,
                                             float* __restrict__ rgb) {
    int b = blockIdx.y;
    int o0 = blockIdx.x * 512;
    int t = threadIdx.x;
    __shared__ float ss[F];
    __shared__ float pre[258];
    if (t < F) ss[t] = srgbS[b * F + t];
    __syncthreads();
    int j0 = (o0 >> 1) - 1;
    for (int jj = t; jj < 258; jj += 256) {
        int j = j0 + jj;
        j = j < 0 ? 0 : (j > LU - 1 ? LU - 1 : j);
        float acc = prev[b * LU + j];
        const float* xb = xf + (size_t)b * S + j;
        for (int f = 0; f < F; ++f) acc += xb[(size_t)f * LU] * ss[f];
        pre[jj] = acc;
    }
    __syncthreads();
    int jj = t + 1;
    int j = j0 + jj;
    float ve = (j == 0) ? pre[jj] : (0.25f * pre[jj - 1] + 0.75f * pre[jj]);
    float vo = 0.75f * pre[jj] + 0.25f * pre[jj + 1];
    float2 v2 = make_float2(ve, vo);
    *(float2*)&rgb[(size_t)b * 2 * LU + o0 + 2 * t] = v2;
}

extern "C" void kernel_launch(void* const* d_in, const int* in_sizes, int n_in,
                              void* d_out, int out_size, void* d_ws, size_t ws_size,
                              hipStream_t stream) {
    const float* x      = (const float*)d_in[0];
    const float* prev   = (const float*)d_in[1];
    const float* istyle = (const float*)d_in[2];
    const float* inoise = (const float*)d_in[3];
    const float* s1w    = (const float*)d_in[4];
    const float* s1b    = (const float*)d_in[5];
    const float* W1     = (const float*)d_in[6];
    const float* nw1    = (const float*)d_in[7];
    const float* s2w    = (const float*)d_in[8];
    const float* s2b    = (const float*)d_in[9];
    const float* W2     = (const float*)d_in[10];
    const float* nw2    = (const float*)d_in[11];
    const float* rgbw   = (const float*)d_in[12];
    const float* rgbb   = (const float*)d_in[13];
    const float* rgbcw  = (const float*)d_in[14];

    char* w = (char*)d_ws;
    float* s1      = (float*)(w);                             // 8 KB
    float* s2      = (float*)(w + 8 * 1024);                  // 4 KB
    float* srgbS   = (float*)(w + 12 * 1024);                 // 4 KB
    float* d1      = (float*)(w + 16 * 1024);                 // 4 KB
    float* d2      = (float*)(w + 20 * 1024);                 // 4 KB
    unsigned short* Wt1 = (unsigned short*)(w + 256 * 1024);  // 192 KB
    unsigned short* Wt2 = (unsigned short*)(w + 448 * 1024);  // 96 KB
    unsigned short* y1  = (unsigned short*)(w + (size_t)1024 * 1024);  // 8 MB

    unsigned short* xt = (unsigned short*)d_out;  // parked; dead once conv2 writes xout

    float* xout   = (float*)d_out;
    float* rgbout = xout + (size_t)B * S;

    k_styles<<<8, 256, 0, stream>>>(istyle, s1w, s1b, s2w, s2b, rgbw, rgbb, rgbcw,
                                    W1, W2, s1, s2, srgbS, d1, d2);
    k_prepw<<<(3 * F * CIN) / 256, 256, 0, stream>>>(W1, W2, Wt1, Wt2);
    k_prepx<<<dim3(LU / 64, CIN / 64, B), 256, 0, stream>>>(x, s1, xt);
    k_conv1<<<dim3(LU / 64, B / 2, 2), 256, 0, stream>>>(xt, Wt1, d1, y1);
    k_noise1<<<S / 256, 256, 0, stream>>>(y1, nw1, inoise, s2);
    k_conv2<<<dim3(LU / 64, B / 2, 2), 256, 0, stream>>>(y1, Wt2, d2, xout);
    k_noise2<<<S / 256, 256, 0, stream>>>(nw2, inoise, xout);
    k_rgb<<<dim3(2 * LU / 512, B), 256, 0, stream>>>(xout, srgbS, prev, rgbout);
}